// Round 3
// baseline (273.984 us; speedup 1.0000x reference)
//
#include <hip/hip_runtime.h>

// Closs: B=8192 rows, N=2048 cols, half=1024.
// Per row: acc = sum_j (f[N-1-j] - f[j])                      (the "l" term)
//              + sum_{i=0}^{half-1} [ log S+_i + log S-_i ]
// where S±_i = sum_{j=i}^{half-1} ( exp(±f[j]) + exp(±f[N-1-j]) )
//   -> suffix sums of pairwise e±_j  -> prefix scan after index reversal.
// f ~ N(0,1) so direct exp-sums are safe in fp32 (no max subtraction needed).
// Fused: last-block-done pattern does the deterministic double-precision
// final reduction inside the same kernel (saves the 2nd launch).

#define NCOLS 2048
#define HALF  1024
#define TPB   256   // 4 pairs per thread

__global__ __launch_bounds__(TPB) void closs_fused_kernel(const float* __restrict__ f,
                                                          float* __restrict__ partial,
                                                          unsigned int* __restrict__ cnt,
                                                          float* __restrict__ out,
                                                          int Brows) {
    const int row = blockIdx.x;
    const float* fr = f + (size_t)row * NCOLS;
    const int t    = threadIdx.x;
    const int lane = t & 63;
    const int wave = t >> 6;

    // Thread t owns k = 4t..4t+3 (k = distance from innermost window),
    // i.e. j in [1020-4t, 1024-4t). Both loads are 16B-aligned float4 and
    // fully coalesced across the block.
    const int jbase = HALF - 4 - 4 * t;                 // 1020 - 4t
    const float4 lo = *reinterpret_cast<const float4*>(fr + jbase);
    const float4 hi = *reinterpret_cast<const float4*>(fr + (NCOLS - 4 - jbase)); // mirrors
    const float* lop = reinterpret_cast<const float*>(&lo);
    const float* hip_ = reinterpret_cast<const float*>(&hi);

    // pair q (k = 4t+q): low = lo[3-q], mirror = hi[q]
    float pp[4], pm[4];          // intra-thread inclusive prefix of e+ / e-
    float sp = 0.f, sm = 0.f;    // thread totals
    float lsum = 0.f;            // contribution to l
    #pragma unroll
    for (int q = 0; q < 4; ++q) {
        const float a = lop[3 - q];
        const float b = hip_[q];
        const float ep = __expf(a) + __expf(b);
        const float em = __expf(-a) + __expf(-b);
        sp += ep; pp[q] = sp;
        sm += em; pm[q] = sm;
        lsum += b - a;
    }

    // Wave-level inclusive scan of thread totals (64 lanes).
    float ip = sp, im = sm;
    #pragma unroll
    for (int d = 1; d < 64; d <<= 1) {
        const float op = __shfl_up(ip, d, 64);
        const float om = __shfl_up(im, d, 64);
        if (lane >= d) { ip += op; im += om; }
    }

    // Cross-wave exclusive offsets (4 waves).
    __shared__ float wtp[4], wtm[4], cw[4];
    __shared__ bool lastFlag;
    if (lane == 63) { wtp[wave] = ip; wtm[wave] = im; }
    __syncthreads();
    float offp = ip - sp;   // exclusive-within-wave
    float offm = im - sm;
    #pragma unroll
    for (int w = 0; w < 3; ++w) {
        if (w < wave) { offp += wtp[w]; offm += wtm[w]; }
    }

    // 8 logs per thread + l contribution.
    float c = lsum;
    #pragma unroll
    for (int q = 0; q < 4; ++q) {
        c += __logf(offp + pp[q]) + __logf(offm + pm[q]);
    }

    // Block reduction.
    #pragma unroll
    for (int d = 32; d > 0; d >>= 1) c += __shfl_down(c, d, 64);
    if (lane == 0) cw[wave] = c;
    __syncthreads();

    // Publish partial; last block to finish does the final reduction.
    if (t == 0) {
        partial[row] = cw[0] + cw[1] + cw[2] + cw[3];
        __threadfence();                               // release (device scope)
        const unsigned int old = atomicAdd(cnt, 1u);
        lastFlag = (old == (unsigned int)Brows - 1u);
    }
    __syncthreads();
    if (!lastFlag) return;

    __threadfence();                                   // acquire (invalidate caches)
    __shared__ double sd[TPB];
    double s = 0.0;
    for (int i = t; i < Brows; i += TPB) s += (double)partial[i];
    sd[t] = s;
    __syncthreads();
    for (int step = TPB / 2; step > 0; step >>= 1) {
        if (t < step) sd[t] += sd[t + step];
        __syncthreads();
    }
    if (t == 0) out[0] = (float)(sd[0] / (double)Brows);
}

extern "C" void kernel_launch(void* const* d_in, const int* in_sizes, int n_in,
                              void* d_out, int out_size, void* d_ws, size_t ws_size,
                              hipStream_t stream) {
    const float* f = (const float*)d_in[0];
    const int Brows = in_sizes[0] / NCOLS;                  // 8192
    float* partial = (float*)d_ws;                          // Brows floats
    unsigned int* cnt = (unsigned int*)((char*)d_ws + (size_t)Brows * sizeof(float));

    hipMemsetAsync(cnt, 0, sizeof(unsigned int), stream);   // graph-capturable memset node
    closs_fused_kernel<<<Brows, TPB, 0, stream>>>(f, partial, cnt, (float*)d_out, Brows);
}

// Round 4
// 95.780 us; speedup vs baseline: 2.8606x; 2.8606x over previous
//
#include <hip/hip_runtime.h>

// Closs: B=8192 rows, N=2048 cols, half=1024.
// Per row: acc = sum_j (f[N-1-j] - f[j])                      (the "l" term)
//              + sum_{i=0}^{half-1} [ log S+_i + log S-_i ]
// where S±_i = sum_{j=i}^{half-1} ( exp(±f[j]) + exp(±f[N-1-j]) )
//   -> suffix sums of pairwise e±_j  -> inclusive prefix scan after index
//      reversal (k = half-1-j). f ~ N(0,1): direct exp is safe in fp32.
//
// Structure: ONE WAVE PER ROW, 16 pairs/lane. No LDS, no __syncthreads.
// Trans-op diet: e-_pair = ep * rcp(ea*eb)   (2 exp + 1 rcp, not 4 exp)
//               logS+ + logS- = log(S+ * S-) (1 log, not 2)
// R3 lesson: NO single-counter atomic fan-in (8192 contended atomics = +220us).

#define NCOLS 2048
#define HALF  1024
#define PAIRS 16    // pairs per lane; 64 lanes * 16 = 1024 pairs = one row

__global__ __launch_bounds__(256) void closs_row_kernel(const float* __restrict__ f,
                                                        float* __restrict__ partial) {
    const int lane = threadIdx.x & 63;
    const int row  = blockIdx.x * 4 + (threadIdx.x >> 6);   // 4 waves, 4 rows/block
    const float* fr = f + (size_t)row * NCOLS;

    // Lane owns k in [16*lane, 16*lane+16).
    // low side:  j = 1023-k  -> 16 floats ascending at fr + 1008 - 16*lane
    // high side: j'= 1024+k  -> 16 floats ascending at fr + 1024 + 16*lane
    const float* lo_base = fr + (HALF - PAIRS - PAIRS * lane);
    const float* hi_base = fr + (HALF + PAIRS * lane);

    float lov[PAIRS], hiv[PAIRS];
    #pragma unroll
    for (int q = 0; q < PAIRS / 4; ++q) {
        const float4 lv = *reinterpret_cast<const float4*>(lo_base + 4 * q);
        const float4 hv = *reinterpret_cast<const float4*>(hi_base + 4 * q);
        lov[4 * q + 0] = lv.x; lov[4 * q + 1] = lv.y;
        lov[4 * q + 2] = lv.z; lov[4 * q + 3] = lv.w;
        hiv[4 * q + 0] = hv.x; hiv[4 * q + 1] = hv.y;
        hiv[4 * q + 2] = hv.z; hiv[4 * q + 3] = hv.w;
    }

    // pair p (k = 16*lane + p): a = lov[15-p], b = hiv[p]
    float pp[PAIRS], pm[PAIRS];       // intra-lane inclusive prefixes of e+ / e-
    float sp = 0.f, sm = 0.f, lsum = 0.f;
    #pragma unroll
    for (int p = 0; p < PAIRS; ++p) {
        const float a  = lov[PAIRS - 1 - p];
        const float b  = hiv[p];
        const float ea = __expf(a);
        const float eb = __expf(b);
        const float ep = ea + eb;                                  // e^a + e^b
        const float em = ep * __builtin_amdgcn_rcpf(ea * eb);      // e^-a + e^-b (exact algebra)
        sp += ep; pp[p] = sp;
        sm += em; pm[p] = sm;
        lsum += b - a;
    }

    // Wave-level inclusive scan of lane totals (64 lanes).
    float ip = sp, im = sm;
    #pragma unroll
    for (int d = 1; d < 64; d <<= 1) {
        const float op = __shfl_up(ip, d, 64);
        const float om = __shfl_up(im, d, 64);
        if (lane >= d) { ip += op; im += om; }
    }
    const float offp = ip - sp;       // exclusive offset for this lane
    const float offm = im - sm;

    // 16 fused logs per lane + l contribution.
    float c = lsum;
    #pragma unroll
    for (int p = 0; p < PAIRS; ++p) {
        c += __logf((offp + pp[p]) * (offm + pm[p]));
    }

    // Wave butterfly reduction; lane 0 writes the row partial. No LDS needed.
    #pragma unroll
    for (int d = 32; d > 0; d >>= 1) c += __shfl_xor(c, d, 64);
    if (lane == 0) partial[row] = c;
}

__global__ __launch_bounds__(256) void closs_reduce_kernel(const float* __restrict__ partial,
                                                           float* __restrict__ out,
                                                           int n, double inv) {
    __shared__ double sd[256];
    const int t = threadIdx.x;
    double s = 0.0;
    for (int i = t * 4; i < n; i += 256 * 4) {
        const float4 v = *reinterpret_cast<const float4*>(partial + i);
        s += (double)v.x + (double)v.y + (double)v.z + (double)v.w;
    }
    sd[t] = s;
    __syncthreads();
    for (int step = 128; step > 0; step >>= 1) {
        if (t < step) sd[t] += sd[t + step];
        __syncthreads();
    }
    if (t == 0) out[0] = (float)(sd[0] * inv);
}

extern "C" void kernel_launch(void* const* d_in, const int* in_sizes, int n_in,
                              void* d_out, int out_size, void* d_ws, size_t ws_size,
                              hipStream_t stream) {
    const float* f = (const float*)d_in[0];
    const int Brows = in_sizes[0] / NCOLS;       // 8192
    float* partial = (float*)d_ws;               // Brows floats of scratch

    closs_row_kernel<<<Brows / 4, 256, 0, stream>>>(f, partial);
    closs_reduce_kernel<<<1, 256, 0, stream>>>(partial, (float*)d_out,
                                               Brows, 1.0 / (double)Brows);
}